// Round 1
// baseline (2397.778 us; speedup 1.0000x reference)
//
#include <hip/hip_runtime.h>
#include <math.h>

// Net: ConvLSTM(32)->pool->ConvLSTM(48)->pool->conv3+ELU->conv4(1x1)+ELU->conv5(1x1)
// B=8, T=32, H=8, W=256, F1=32, F2=48, F3=256, F4=128, NNOTE=88
// fp32 baseline, one fused kernel per LSTM timestep.

#define DEVINL static __device__ __forceinline__

DEVINL float sigm(float x) { return 1.0f / (1.0f + __expf(-x)); }
DEVINL float tanh_fast(float x) { return 1.0f - 2.0f / (__expf(2.0f * x) + 1.0f); }
DEVINL float elu(float x) { return x > 0.0f ? x : expm1f(x); }

// ---------------- LSTM1 fused step ----------------
// grid (4,8,8) = (xq, y, b), block 512.
// Each block: 64 x-positions, all 128 gate channels; wave cg owns 16 channels
// (wave-uniform -> scalar weight loads). z exchanged via LDS, gates fused.
__global__ __launch_bounds__(512) void lstm1_step(
    const float* __restrict__ xin,   // (8,1,32,8,256)
    const float* __restrict__ w1,    // (128,33,3,3)
    const float* __restrict__ b1,    // (128)
    const float* __restrict__ hprev, // (8,32,8,256)
    float* __restrict__ hout,        // (8,32,8,256)
    float* __restrict__ c1,          // (8,32,8,256)
    int t)
{
    __shared__ float sIn[33 * 3 * 66];  // [ci][dy][lx], lx = x - x0 + 1
    __shared__ float sZ[128 * 64];
    const int xq = blockIdx.x, y = blockIdx.y, b = blockIdx.z;
    const int x0 = xq * 64;
    const int tid = threadIdx.x;

    for (int idx = tid; idx < 33 * 198; idx += 512) {
        int ci = idx / 198, rem = idx % 198;
        int dy = rem / 66, lx = rem % 66;
        int gy = y + dy - 1, gx = x0 + lx - 1;
        float v = 0.0f;
        if (gy >= 0 && gy < 8 && gx >= 0 && gx < 256) {
            v = (ci == 0) ? xin[((b * 32 + t) * 8 + gy) * 256 + gx]
                          : hprev[((b * 32 + (ci - 1)) * 8 + gy) * 256 + gx];
        }
        sIn[idx] = v;
    }
    __syncthreads();

    const int p = tid & 63;
    const int cg = __builtin_amdgcn_readfirstlane(tid >> 6); // 0..7, wave-uniform
    const int co0 = cg * 16;
    float acc[16];
#pragma unroll
    for (int j = 0; j < 16; ++j) acc[j] = b1[co0 + j];

    for (int ci = 0; ci < 33; ++ci) {
#pragma unroll
        for (int dy = 0; dy < 3; ++dy) {
            const float* srow = &sIn[(ci * 3 + dy) * 66 + p];
            float v0 = srow[0], v1 = srow[1], v2 = srow[2];
            const float* wp = &w1[co0 * 297 + ci * 9 + dy * 3]; // w1[co][ci][dy][dx]
#pragma unroll
            for (int j = 0; j < 16; ++j) {
                acc[j] = fmaf(v0, wp[j * 297 + 0], acc[j]);
                acc[j] = fmaf(v1, wp[j * 297 + 1], acc[j]);
                acc[j] = fmaf(v2, wp[j * 297 + 2], acc[j]);
            }
        }
    }
#pragma unroll
    for (int j = 0; j < 16; ++j) sZ[(co0 + j) * 64 + p] = acc[j];
    __syncthreads();

    // gates: i=[0:32) f=[32:64) g=[64:96) o=[96:128)
    for (int e = tid; e < 32 * 64; e += 512) {
        int f = e >> 6, pp = e & 63;
        float zi = sZ[f * 64 + pp];
        float zf = sZ[(f + 32) * 64 + pp];
        float zg = sZ[(f + 64) * 64 + pp];
        float zo = sZ[(f + 96) * 64 + pp];
        int gidx = ((b * 32 + f) * 8 + y) * 256 + x0 + pp;
        float cv = c1[gidx];
        float cn = sigm(zf) * cv + sigm(zi) * tanh_fast(zg);
        float hn = sigm(zo) * tanh_fast(cn);
        c1[gidx] = cn;
        hout[gidx] = hn;
    }
}

// ---------------- pool after LSTM1 (at odd t) ----------------
// p1: (8,32,16,4,128); one thread per pooled element of slot tp.
__global__ void pool1(const float* __restrict__ he, const float* __restrict__ ho,
                      float* __restrict__ p1, int tp)
{
    int idx = blockIdx.x * 256 + threadIdx.x;
    if (idx >= 8 * 32 * 4 * 128) return;
    int xp = idx & 127, t1 = idx >> 7;
    int yp = t1 & 3, t2 = t1 >> 2;
    int f = t2 & 31, b = t2 >> 5;
    int base = ((b * 32 + f) * 8 + yp * 2) * 256 + xp * 2;
    float m = he[base];
    m = fmaxf(m, he[base + 1]);
    m = fmaxf(m, he[base + 256]);
    m = fmaxf(m, he[base + 257]);
    m = fmaxf(m, ho[base]);
    m = fmaxf(m, ho[base + 1]);
    m = fmaxf(m, ho[base + 256]);
    m = fmaxf(m, ho[base + 257]);
    p1[(((b * 32 + f) * 16 + tp) * 4 + yp) * 128 + xp] = m;
}

// ---------------- LSTM2: z = conv(concat(xt,h)) ----------------
// grid (8,4,8) = (xh*?+cq packed, y, b): blockIdx.x -> xh = &1, cq = >>1.
// Each block: 64 x-positions, 48 of 192 channels; wave owns 6 channels.
__global__ __launch_bounds__(512) void lstm2_z(
    const float* __restrict__ p1,    // (8,32,16,4,128)
    const float* __restrict__ w2,    // (192,80,3,3)
    const float* __restrict__ b2,    // (192)
    const float* __restrict__ hprev, // (8,48,4,128)
    float* __restrict__ z2,          // (8,192,4,128)
    int t)
{
    __shared__ float sIn[80 * 3 * 66];
    const int bx = blockIdx.x, y = blockIdx.y, b = blockIdx.z;
    const int xh = bx & 1, cq = bx >> 1;
    const int x0 = xh * 64;
    const int tid = threadIdx.x;

    for (int idx = tid; idx < 80 * 198; idx += 512) {
        int ci = idx / 198, rem = idx % 198;
        int dy = rem / 66, lx = rem % 66;
        int gy = y + dy - 1, gx = x0 + lx - 1;
        float v = 0.0f;
        if (gy >= 0 && gy < 4 && gx >= 0 && gx < 128) {
            v = (ci < 32) ? p1[(((b * 32 + ci) * 16 + t) * 4 + gy) * 128 + gx]
                          : hprev[((b * 48 + (ci - 32)) * 4 + gy) * 128 + gx];
        }
        sIn[idx] = v;
    }
    __syncthreads();

    const int p = tid & 63;
    const int cg = __builtin_amdgcn_readfirstlane(tid >> 6);
    const int co0 = cq * 48 + cg * 6;
    float acc[6];
#pragma unroll
    for (int j = 0; j < 6; ++j) acc[j] = b2[co0 + j];

    for (int ci = 0; ci < 80; ++ci) {
#pragma unroll
        for (int dy = 0; dy < 3; ++dy) {
            const float* srow = &sIn[(ci * 3 + dy) * 66 + p];
            float v0 = srow[0], v1 = srow[1], v2 = srow[2];
            const float* wp = &w2[co0 * 720 + ci * 9 + dy * 3];
#pragma unroll
            for (int j = 0; j < 6; ++j) {
                acc[j] = fmaf(v0, wp[j * 720 + 0], acc[j]);
                acc[j] = fmaf(v1, wp[j * 720 + 1], acc[j]);
                acc[j] = fmaf(v2, wp[j * 720 + 2], acc[j]);
            }
        }
    }
    const int gx = x0 + p;
#pragma unroll
    for (int j = 0; j < 6; ++j)
        z2[((b * 192 + co0 + j) * 4 + y) * 128 + gx] = acc[j];
}

// ---------------- LSTM2 gates + fused pool (at odd t) ----------------
// One thread per 2x2 spatial patch of one (b,f).
__global__ void lstm2_gate(const float* __restrict__ z2, float* __restrict__ c2,
                           const float* __restrict__ hprevpool,
                           float* __restrict__ hout, float* __restrict__ p2, int t)
{
    int idx = blockIdx.x * 256 + threadIdx.x;
    if (idx >= 8 * 48 * 2 * 64) return;
    int xp = idx & 63; int t1 = idx >> 6;
    int yp = t1 & 1; t1 >>= 1;
    int f = t1 % 48; int b = t1 / 48;
    float m = -INFINITY;
#pragma unroll
    for (int dy = 0; dy < 2; ++dy) {
#pragma unroll
        for (int dx = 0; dx < 2; ++dx) {
            int y = yp * 2 + dy, xx = xp * 2 + dx;
            int zbase = ((b * 192 + f) * 4 + y) * 128 + xx;
            float zi = z2[zbase];
            float zf = z2[zbase + 48 * 512];
            float zg = z2[zbase + 96 * 512];
            float zo = z2[zbase + 144 * 512];
            int gidx = ((b * 48 + f) * 4 + y) * 128 + xx;
            float cv = c2[gidx];
            float cn = sigm(zf) * cv + sigm(zi) * tanh_fast(zg);
            float hn = sigm(zo) * tanh_fast(cn);
            c2[gidx] = cn;
            hout[gidx] = hn;
            m = fmaxf(m, hn);
            if (t & 1) m = fmaxf(m, hprevpool[gidx]);
        }
    }
    if (t & 1) {
        int tp = t >> 1;
        p2[(((b * 48 + f) * 8 + tp) * 2 + yp) * 64 + xp] = m;
    }
}

// ---------------- conv3 (K-split partials) ----------------
// in3 = p2 reinterpreted as (8,48,16,64) (flat layouts identical).
// grid (2,16,8) = (nh, kq, b); block 256: n = nh*128+(tid&127), rh = tid>>7.
__global__ __launch_bounds__(256) void conv3_part(
    const float* __restrict__ in3,  // (8,48,16,64)
    const float* __restrict__ w3T,  // (9216,256)
    float* __restrict__ part)       // (16,8,256,14)
{
    __shared__ float sIn[3 * 16 * 64];
    const int nh = blockIdx.x, kq = blockIdx.y, b = blockIdx.z;
    const int tid = threadIdx.x;
    const int c0 = kq * 3;
    for (int idx = tid; idx < 3 * 16 * 64; idx += 256) {
        int w = idx & 63, t1 = idx >> 6;
        int r = t1 & 15, cl = t1 >> 4;
        sIn[idx] = in3[((b * 48 + c0 + cl) * 16 + r) * 64 + w];
    }
    __syncthreads();
    const int n = nh * 128 + (tid & 127);
    const int rh = tid >> 7; // 0..1 -> rows [0,7) / [7,14)
    float acc[7];
#pragma unroll
    for (int r = 0; r < 7; ++r) acc[r] = 0.0f;
    for (int cl = 0; cl < 3; ++cl)
        for (int dr = 0; dr < 3; ++dr)
            for (int w = 0; w < 64; ++w) {
                int k = ((c0 + cl) * 3 + dr) * 64 + w;
                float wt = w3T[k * 256 + n];
                const float* ip = &sIn[(cl * 16 + dr + rh * 7) * 64 + w];
#pragma unroll
                for (int r = 0; r < 7; ++r)
                    acc[r] = fmaf(ip[r * 64], wt, acc[r]);
            }
    float* pp = &part[((kq * 8 + b) * 256 + n) * 14 + rh * 7];
#pragma unroll
    for (int r = 0; r < 7; ++r) pp[r] = acc[r];
}

__global__ void conv3_reduce(const float* __restrict__ part,
                             const float* __restrict__ b3, float* __restrict__ out3)
{
    int idx = blockIdx.x * 256 + threadIdx.x;
    if (idx >= 8 * 256 * 14) return;
    int r = idx % 14, t1 = idx / 14;
    int n = t1 & 255, b = t1 >> 8;
    float s = b3[n];
#pragma unroll
    for (int kq = 0; kq < 16; ++kq)
        s += part[((kq * 8 + b) * 256 + n) * 14 + r];
    out3[idx] = elu(s);   // out3: (8,256,14)
}

// ---------------- conv4 (1x1, 256->128) + ELU ----------------
__global__ __launch_bounds__(128) void conv4(
    const float* __restrict__ out3, const float* __restrict__ w4T,
    const float* __restrict__ b4, float* __restrict__ out4)
{
    const int r = blockIdx.x, b = blockIdx.y, n = threadIdx.x;
    float acc = b4[n];
    for (int cc = 0; cc < 256; ++cc)
        acc = fmaf(out3[(b * 256 + cc) * 14 + r], w4T[cc * 128 + n], acc);
    out4[(b * 128 + n) * 14 + r] = elu(acc); // (8,128,14)
}

// ---------------- conv5 (1x1, 128->88) ----------------
__global__ __launch_bounds__(128) void conv5(
    const float* __restrict__ out4, const float* __restrict__ w5T,
    const float* __restrict__ b5, float* __restrict__ outp)
{
    const int r = blockIdx.x, b = blockIdx.y, n = threadIdx.x;
    if (n >= 88) return;
    float acc = b5[n];
    for (int cc = 0; cc < 128; ++cc)
        acc = fmaf(out4[(b * 128 + cc) * 14 + r], w5T[cc * 88 + n], acc);
    outp[(b * 88 + n) * 14 + r] = acc; // (8,88,14,1)
}

// ---------------- weight transposes for coalesced lane-n loads ----------------
__global__ void prep(const float* __restrict__ w3, const float* __restrict__ w4,
                     const float* __restrict__ w5, float* __restrict__ w3T,
                     float* __restrict__ w4T, float* __restrict__ w5T)
{
    int idx = blockIdx.x * 256 + threadIdx.x;
    if (idx < 2359296) {                       // w3 (256,9216) -> (9216,256)
        int n = idx / 9216, k = idx % 9216;
        w3T[k * 256 + n] = w3[idx];
    } else if (idx < 2359296 + 32768) {        // w4 (128,256) -> (256,128)
        int i = idx - 2359296;
        int n = i / 256, c = i % 256;
        w4T[c * 128 + n] = w4[i];
    } else if (idx < 2359296 + 32768 + 11264) { // w5 (88,128) -> (128,88)
        int i = idx - 2359296 - 32768;
        int n = i / 128, c = i % 128;
        w5T[c * 88 + n] = w5[i];
    }
}

extern "C" void kernel_launch(void* const* d_in, const int* in_sizes, int n_in,
                              void* d_out, int out_size, void* d_ws, size_t ws_size,
                              hipStream_t stream)
{
    const float* x  = (const float*)d_in[0];
    const float* w1 = (const float*)d_in[1];
    const float* b1 = (const float*)d_in[2];
    const float* w2 = (const float*)d_in[3];
    const float* b2 = (const float*)d_in[4];
    const float* w3 = (const float*)d_in[5];
    const float* b3 = (const float*)d_in[6];
    const float* w4 = (const float*)d_in[7];
    const float* b4 = (const float*)d_in[8];
    const float* w5 = (const float*)d_in[9];
    const float* b5 = (const float*)d_in[10];
    float* out = (float*)d_out;

    // workspace layout (floats); total ~8.35M floats ~= 33.4 MB
    float* ws = (float*)d_ws;
    size_t off = 0;
    auto alloc = [&](size_t n) { float* p = ws + off; off += n; return p; };
    float* h1[2]; h1[0] = alloc(524288); h1[1] = alloc(524288); // (8,32,8,256)
    float* c1 = alloc(524288);
    float* p1 = alloc(2097152);  // (8,32,16,4,128)
    float* h2[2]; h2[0] = alloc(196608); h2[1] = alloc(196608); // (8,48,4,128)
    float* c2 = alloc(196608);
    float* z2 = alloc(786432);   // (8,192,4,128)
    float* p2 = alloc(393216);   // (8,48,8,2,64) == (8,48,16,64)
    float* part3 = alloc(458752);// (16,8,256,14)
    float* out3 = alloc(28672);  // (8,256,14)
    float* out4 = alloc(14336);  // (8,128,14)
    float* w3T = alloc(2359296);
    float* w4T = alloc(32768);
    float* w5T = alloc(11264);
    (void)ws_size; (void)off;

    hipMemsetAsync(h1[1], 0, 524288 * sizeof(float), stream);
    hipMemsetAsync(c1,    0, 524288 * sizeof(float), stream);
    hipMemsetAsync(h2[1], 0, 196608 * sizeof(float), stream);
    hipMemsetAsync(c2,    0, 196608 * sizeof(float), stream);

    prep<<<9388, 256, 0, stream>>>(w3, w4, w5, w3T, w4T, w5T);

    for (int t = 0; t < 32; ++t) {
        lstm1_step<<<dim3(4, 8, 8), 512, 0, stream>>>(
            x, w1, b1, h1[1 - (t & 1)], h1[t & 1], c1, t);
        if (t & 1)
            pool1<<<512, 256, 0, stream>>>(h1[0], h1[1], p1, t >> 1);
    }
    for (int t = 0; t < 16; ++t) {
        lstm2_z<<<dim3(8, 4, 8), 512, 0, stream>>>(
            p1, w2, b2, h2[1 - (t & 1)], z2, t);
        lstm2_gate<<<192, 256, 0, stream>>>(
            z2, c2, h2[1 - (t & 1)], h2[t & 1], p2, t);
    }
    conv3_part<<<dim3(2, 16, 8), 256, 0, stream>>>(p2, w3T, part3);
    conv3_reduce<<<112, 256, 0, stream>>>(part3, b3, out3);
    conv4<<<dim3(14, 8), 128, 0, stream>>>(out3, w4T, b4, out4);
    conv5<<<dim3(14, 8), 128, 0, stream>>>(out4, w5T, b5, out);
}

// Round 2
// 1560.630 us; speedup vs baseline: 1.5364x; 1.5364x over previous
//
#include <hip/hip_runtime.h>
#include <math.h>

// Net: ConvLSTM(32)->pool->ConvLSTM(48)->pool->conv3+ELU->conv4(1x1)+ELU->conv5(1x1)
// B=8, T=32, H=8, W=256, F1=32, F2=48, F3=256, F4=128, NNOTE=88
// fp32, one fused kernel per LSTM timestep.
// R1: k-major per-wave weight layout (s_load-streamable) + in-wave gate fusion.

#define DEVINL static __device__ __forceinline__

DEVINL float sigm(float x) { return 1.0f / (1.0f + __expf(-x)); }
DEVINL float tanh_fast(float x) { return 1.0f - 2.0f / (__expf(2.0f * x) + 1.0f); }
DEVINL float elu(float x) { return x > 0.0f ? x : expm1f(x); }

// ---------------- LSTM1 fused step ----------------
// grid (4,8,8) = (xq, y, b), block 512 = 8 waves.
// Wave w owns co = {gate*32 + w*4 + r : gate in 0..3, r in 0..3} -> gates of
// f = w*4+r all land in one lane; gate math fused, no z exchange.
// Weights pre-transposed: w1G[w][kk=ci*3+dy][dx*16 + (r*4+gate)] contiguous.
__global__ __launch_bounds__(512) void lstm1_step(
    const float* __restrict__ xin,   // (8,1,32,8,256)
    const float* __restrict__ w1G,   // (8,99,48)
    const float* __restrict__ b1,    // (128)
    const float* __restrict__ hprev, // (8,32,8,256)
    float* __restrict__ hout,        // (8,32,8,256)
    float* __restrict__ c1,          // (8,32,8,256)
    int t)
{
    __shared__ float sIn[33 * 3 * 66];  // [ci][dy][lx], lx = x - x0 + 1
    const int xq = blockIdx.x, y = blockIdx.y, b = blockIdx.z;
    const int x0 = xq * 64;
    const int tid = threadIdx.x;

    for (int idx = tid; idx < 33 * 198; idx += 512) {
        int ci = idx / 198, rem = idx % 198;
        int dy = rem / 66, lx = rem % 66;
        int gy = y + dy - 1, gx = x0 + lx - 1;
        float v = 0.0f;
        if (gy >= 0 && gy < 8 && gx >= 0 && gx < 256) {
            v = (ci == 0) ? xin[((b * 32 + t) * 8 + gy) * 256 + gx]
                          : hprev[((b * 32 + (ci - 1)) * 8 + gy) * 256 + gx];
        }
        sIn[idx] = v;
    }
    __syncthreads();

    const int p = tid & 63;
    const int wv = __builtin_amdgcn_readfirstlane(tid >> 6); // 0..7 wave-uniform
    const float* wbase = w1G + wv * 4752;
    float acc[16];
#pragma unroll
    for (int j = 0; j < 16; ++j) acc[j] = b1[(j & 3) * 32 + wv * 4 + (j >> 2)];

    for (int ci = 0; ci < 33; ++ci) {
        const float* sr = &sIn[ci * 198 + p];
        const float* wk = wbase + ci * 144;
#pragma unroll
        for (int dy = 0; dy < 3; ++dy) {
            float v0 = sr[dy * 66], v1 = sr[dy * 66 + 1], v2 = sr[dy * 66 + 2];
            const float* w0 = wk + dy * 48;
#pragma unroll
            for (int j = 0; j < 16; ++j)
                acc[j] = fmaf(v2, w0[32 + j],
                         fmaf(v1, w0[16 + j],
                         fmaf(v0, w0[j], acc[j])));
        }
    }

    // acc[r*4 + gate] : gate 0=i 1=f 2=g 3=o for f = wv*4+r
#pragma unroll
    for (int r = 0; r < 4; ++r) {
        int f = wv * 4 + r;
        int gidx = ((b * 32 + f) * 8 + y) * 256 + x0 + p;
        float zi = acc[r * 4 + 0], zf = acc[r * 4 + 1];
        float zg = acc[r * 4 + 2], zo = acc[r * 4 + 3];
        float cv = c1[gidx];
        float cn = sigm(zf) * cv + sigm(zi) * tanh_fast(zg);
        c1[gidx] = cn;
        hout[gidx] = sigm(zo) * tanh_fast(cn);
    }
}

// ---------------- pool after LSTM1 (at odd t) ----------------
__global__ void pool1(const float* __restrict__ he, const float* __restrict__ ho,
                      float* __restrict__ p1, int tp)
{
    int idx = blockIdx.x * 256 + threadIdx.x;
    if (idx >= 8 * 32 * 4 * 128) return;
    int xp = idx & 127, t1 = idx >> 7;
    int yp = t1 & 3, t2 = t1 >> 2;
    int f = t2 & 31, b = t2 >> 5;
    int base = ((b * 32 + f) * 8 + yp * 2) * 256 + xp * 2;
    float m = he[base];
    m = fmaxf(m, he[base + 1]);
    m = fmaxf(m, he[base + 256]);
    m = fmaxf(m, he[base + 257]);
    m = fmaxf(m, ho[base]);
    m = fmaxf(m, ho[base + 1]);
    m = fmaxf(m, ho[base + 256]);
    m = fmaxf(m, ho[base + 257]);
    p1[(((b * 32 + f) * 16 + tp) * 4 + yp) * 128 + xp] = m;
}

// ---------------- LSTM2: z = conv(concat(xt,h)) ----------------
// grid (8,4,8): bx -> xh=&1, cq=>>1. Wave cg owns 6 channels co = (cq*8+cg)*6+j.
// Weights pre-transposed: w2G[g][kk=ci*3+dy][dx*6+j] contiguous per (ci,dy).
__global__ __launch_bounds__(512) void lstm2_z(
    const float* __restrict__ p1,    // (8,32,16,4,128)
    const float* __restrict__ w2G,   // (32,240,18)
    const float* __restrict__ b2,    // (192)
    const float* __restrict__ hprev, // (8,48,4,128)
    float* __restrict__ z2,          // (8,192,4,128)
    int t)
{
    __shared__ float sIn[80 * 3 * 66];
    const int bx = blockIdx.x, y = blockIdx.y, b = blockIdx.z;
    const int xh = bx & 1, cq = bx >> 1;
    const int x0 = xh * 64;
    const int tid = threadIdx.x;

    for (int idx = tid; idx < 80 * 198; idx += 512) {
        int ci = idx / 198, rem = idx % 198;
        int dy = rem / 66, lx = rem % 66;
        int gy = y + dy - 1, gx = x0 + lx - 1;
        float v = 0.0f;
        if (gy >= 0 && gy < 4 && gx >= 0 && gx < 128) {
            v = (ci < 32) ? p1[(((b * 32 + ci) * 16 + t) * 4 + gy) * 128 + gx]
                          : hprev[((b * 48 + (ci - 32)) * 4 + gy) * 128 + gx];
        }
        sIn[idx] = v;
    }
    __syncthreads();

    const int p = tid & 63;
    const int cg = __builtin_amdgcn_readfirstlane(tid >> 6);
    const int g = cq * 8 + cg;           // 0..31
    const float* wbase = w2G + g * 4320;
    const int co0 = g * 6;
    float acc[6];
#pragma unroll
    for (int j = 0; j < 6; ++j) acc[j] = b2[co0 + j];

    for (int ci = 0; ci < 80; ++ci) {
        const float* sr = &sIn[ci * 198 + p];
        const float* wk = wbase + ci * 54;
#pragma unroll
        for (int dy = 0; dy < 3; ++dy) {
            float v0 = sr[dy * 66], v1 = sr[dy * 66 + 1], v2 = sr[dy * 66 + 2];
            const float* w0 = wk + dy * 18;
#pragma unroll
            for (int j = 0; j < 6; ++j)
                acc[j] = fmaf(v2, w0[12 + j],
                         fmaf(v1, w0[6 + j],
                         fmaf(v0, w0[j], acc[j])));
        }
    }
    const int gx = x0 + p;
#pragma unroll
    for (int j = 0; j < 6; ++j)
        z2[((b * 192 + co0 + j) * 4 + y) * 128 + gx] = acc[j];
}

// ---------------- LSTM2 gates + fused pool (at odd t) ----------------
__global__ void lstm2_gate(const float* __restrict__ z2, float* __restrict__ c2,
                           const float* __restrict__ hprevpool,
                           float* __restrict__ hout, float* __restrict__ p2, int t)
{
    int idx = blockIdx.x * 256 + threadIdx.x;
    if (idx >= 8 * 48 * 2 * 64) return;
    int xp = idx & 63; int t1 = idx >> 6;
    int yp = t1 & 1; t1 >>= 1;
    int f = t1 % 48; int b = t1 / 48;
    float m = -INFINITY;
#pragma unroll
    for (int dy = 0; dy < 2; ++dy) {
#pragma unroll
        for (int dx = 0; dx < 2; ++dx) {
            int y = yp * 2 + dy, xx = xp * 2 + dx;
            int zbase = ((b * 192 + f) * 4 + y) * 128 + xx;
            float zi = z2[zbase];
            float zf = z2[zbase + 48 * 512];
            float zg = z2[zbase + 96 * 512];
            float zo = z2[zbase + 144 * 512];
            int gidx = ((b * 48 + f) * 4 + y) * 128 + xx;
            float cv = c2[gidx];
            float cn = sigm(zf) * cv + sigm(zi) * tanh_fast(zg);
            float hn = sigm(zo) * tanh_fast(cn);
            c2[gidx] = cn;
            hout[gidx] = hn;
            m = fmaxf(m, hn);
            if (t & 1) m = fmaxf(m, hprevpool[gidx]);
        }
    }
    if (t & 1) {
        int tp = t >> 1;
        p2[(((b * 48 + f) * 8 + tp) * 2 + yp) * 64 + xp] = m;
    }
}

// ---------------- conv3 (K-split partials) ----------------
__global__ __launch_bounds__(256) void conv3_part(
    const float* __restrict__ in3,  // (8,48,16,64)
    const float* __restrict__ w3T,  // (9216,256)
    float* __restrict__ part)       // (16,8,256,14)
{
    __shared__ float sIn[3 * 16 * 64];
    const int nh = blockIdx.x, kq = blockIdx.y, b = blockIdx.z;
    const int tid = threadIdx.x;
    const int c0 = kq * 3;
    for (int idx = tid; idx < 3 * 16 * 64; idx += 256) {
        int w = idx & 63, t1 = idx >> 6;
        int r = t1 & 15, cl = t1 >> 4;
        sIn[idx] = in3[((b * 48 + c0 + cl) * 16 + r) * 64 + w];
    }
    __syncthreads();
    const int n = nh * 128 + (tid & 127);
    const int rh = tid >> 7;
    float acc[7];
#pragma unroll
    for (int r = 0; r < 7; ++r) acc[r] = 0.0f;
    for (int cl = 0; cl < 3; ++cl)
        for (int dr = 0; dr < 3; ++dr)
            for (int w = 0; w < 64; ++w) {
                int k = ((c0 + cl) * 3 + dr) * 64 + w;
                float wt = w3T[k * 256 + n];
                const float* ip = &sIn[(cl * 16 + dr + rh * 7) * 64 + w];
#pragma unroll
                for (int r = 0; r < 7; ++r)
                    acc[r] = fmaf(ip[r * 64], wt, acc[r]);
            }
    float* pp = &part[((kq * 8 + b) * 256 + n) * 14 + rh * 7];
#pragma unroll
    for (int r = 0; r < 7; ++r) pp[r] = acc[r];
}

__global__ void conv3_reduce(const float* __restrict__ part,
                             const float* __restrict__ b3, float* __restrict__ out3)
{
    int idx = blockIdx.x * 256 + threadIdx.x;
    if (idx >= 8 * 256 * 14) return;
    int r = idx % 14, t1 = idx / 14;
    int n = t1 & 255, b = t1 >> 8;
    float s = b3[n];
#pragma unroll
    for (int kq = 0; kq < 16; ++kq)
        s += part[((kq * 8 + b) * 256 + n) * 14 + r];
    out3[idx] = elu(s);   // (8,256,14)
}

// ---------------- conv4 (1x1, 256->128) + ELU ----------------
__global__ __launch_bounds__(128) void conv4(
    const float* __restrict__ out3, const float* __restrict__ w4T,
    const float* __restrict__ b4, float* __restrict__ out4)
{
    const int r = blockIdx.x, b = blockIdx.y, n = threadIdx.x;
    float acc = b4[n];
    for (int cc = 0; cc < 256; ++cc)
        acc = fmaf(out3[(b * 256 + cc) * 14 + r], w4T[cc * 128 + n], acc);
    out4[(b * 128 + n) * 14 + r] = elu(acc); // (8,128,14)
}

// ---------------- conv5 (1x1, 128->88) ----------------
__global__ __launch_bounds__(128) void conv5(
    const float* __restrict__ out4, const float* __restrict__ w5T,
    const float* __restrict__ b5, float* __restrict__ outp)
{
    const int r = blockIdx.x, b = blockIdx.y, n = threadIdx.x;
    if (n >= 88) return;
    float acc = b5[n];
    for (int cc = 0; cc < 128; ++cc)
        acc = fmaf(out4[(b * 128 + cc) * 14 + r], w5T[cc * 88 + n], acc);
    outp[(b * 88 + n) * 14 + r] = acc; // (8,88,14,1)
}

// ---------------- weight re-layouts ----------------
// w1G[w][kk][dx*16+j]  (8,99,48):   co = (j&3)*32 + w*4 + (j>>2), k = ci*9+dy*3+dx
// w2G[g][kk][dx*6+j]   (32,240,18): co = g*6+j
// w3T (9216,256), w4T (256,128), w5T (128,88)
__global__ void prep(const float* __restrict__ w1, const float* __restrict__ w2,
                     const float* __restrict__ w3, const float* __restrict__ w4,
                     const float* __restrict__ w5, float* __restrict__ w1G,
                     float* __restrict__ w2G, float* __restrict__ w3T,
                     float* __restrict__ w4T, float* __restrict__ w5T)
{
    int idx = blockIdx.x * 256 + threadIdx.x;
    if (idx < 38016) {                          // w1G
        int w = idx / 4752, rem = idx % 4752;
        int kk = rem / 48, dd = rem % 48;
        int dx = dd >> 4, j = dd & 15;
        int ci = kk / 3, dy = kk % 3;
        int co = (j & 3) * 32 + w * 4 + (j >> 2);
        w1G[idx] = w1[co * 297 + ci * 9 + dy * 3 + dx];
        return;
    }
    idx -= 38016;
    if (idx < 138240) {                         // w2G
        int g = idx / 4320, rem = idx % 4320;
        int kk = rem / 18, dd = rem % 18;
        int dx = dd / 6, j = dd % 6;
        int ci = kk / 3, dy = kk % 3;
        int co = g * 6 + j;
        w2G[idx] = w2[co * 720 + ci * 9 + dy * 3 + dx];
        return;
    }
    idx -= 138240;
    if (idx < 2359296) {                        // w3 (256,9216) -> (9216,256)
        int n = idx / 9216, k = idx % 9216;
        w3T[k * 256 + n] = w3[idx];
        return;
    }
    idx -= 2359296;
    if (idx < 32768) {                          // w4 (128,256) -> (256,128)
        int n = idx / 256, c = idx % 256;
        w4T[c * 128 + n] = w4[idx];
        return;
    }
    idx -= 32768;
    if (idx < 11264) {                          // w5 (88,128) -> (128,88)
        int n = idx / 128, c = idx % 128;
        w5T[c * 88 + n] = w5[idx];
    }
}

extern "C" void kernel_launch(void* const* d_in, const int* in_sizes, int n_in,
                              void* d_out, int out_size, void* d_ws, size_t ws_size,
                              hipStream_t stream)
{
    const float* x  = (const float*)d_in[0];
    const float* w1 = (const float*)d_in[1];
    const float* b1 = (const float*)d_in[2];
    const float* w2 = (const float*)d_in[3];
    const float* b2 = (const float*)d_in[4];
    const float* w3 = (const float*)d_in[5];
    const float* b3 = (const float*)d_in[6];
    const float* w4 = (const float*)d_in[7];
    const float* b4 = (const float*)d_in[8];
    const float* w5 = (const float*)d_in[9];
    const float* b5 = (const float*)d_in[10];
    float* out = (float*)d_out;

    float* ws = (float*)d_ws;
    size_t off = 0;
    auto alloc = [&](size_t n) { float* p = ws + off; off += n; return p; };
    float* h1[2]; h1[0] = alloc(524288); h1[1] = alloc(524288); // (8,32,8,256)
    float* c1 = alloc(524288);
    float* p1 = alloc(2097152);  // (8,32,16,4,128)
    float* h2[2]; h2[0] = alloc(196608); h2[1] = alloc(196608); // (8,48,4,128)
    float* c2 = alloc(196608);
    float* z2 = alloc(786432);   // (8,192,4,128)
    float* p2 = alloc(393216);   // (8,48,16,64)
    float* part3 = alloc(458752);// (16,8,256,14)
    float* out3 = alloc(28672);  // (8,256,14)
    float* out4 = alloc(14336);  // (8,128,14)
    float* w1G = alloc(38016);
    float* w2G = alloc(138240);
    float* w3T = alloc(2359296);
    float* w4T = alloc(32768);
    float* w5T = alloc(11264);
    (void)ws_size; (void)off;

    hipMemsetAsync(h1[1], 0, 524288 * sizeof(float), stream);
    hipMemsetAsync(c1,    0, 524288 * sizeof(float), stream);
    hipMemsetAsync(h2[1], 0, 196608 * sizeof(float), stream);
    hipMemsetAsync(c2,    0, 196608 * sizeof(float), stream);

    prep<<<10078, 256, 0, stream>>>(w1, w2, w3, w4, w5, w1G, w2G, w3T, w4T, w5T);

    for (int t = 0; t < 32; ++t) {
        lstm1_step<<<dim3(4, 8, 8), 512, 0, stream>>>(
            x, w1G, b1, h1[1 - (t & 1)], h1[t & 1], c1, t);
        if (t & 1)
            pool1<<<512, 256, 0, stream>>>(h1[0], h1[1], p1, t >> 1);
    }
    for (int t = 0; t < 16; ++t) {
        lstm2_z<<<dim3(8, 4, 8), 512, 0, stream>>>(
            p1, w2G, b2, h2[1 - (t & 1)], z2, t);
        lstm2_gate<<<192, 256, 0, stream>>>(
            z2, c2, h2[1 - (t & 1)], h2[t & 1], p2, t);
    }
    conv3_part<<<dim3(2, 16, 8), 256, 0, stream>>>(p2, w3T, part3);
    conv3_reduce<<<112, 256, 0, stream>>>(part3, b3, out3);
    conv4<<<dim3(14, 8), 128, 0, stream>>>(out3, w4T, b4, out4);
    conv5<<<dim3(14, 8), 128, 0, stream>>>(out4, w5T, b5, out);
}

// Round 3
// 1206.024 us; speedup vs baseline: 1.9882x; 1.2940x over previous
//
#include <hip/hip_runtime.h>
#include <math.h>

// Net: ConvLSTM(32)->pool->ConvLSTM(48)->pool->conv3+ELU->conv4(1x1)+ELU->conv5(1x1)
// B=8, T=32, H=8, W=256, F1=32, F2=48, F3=256, F4=128, NNOTE=88
// R2: LSTM1 conv -> split-bf16 MFMA (3-term, ~fp32 accuracy), in-lane gate fusion
//     via A-row permutation. LSTM2/conv3 paths unchanged from R1.

#define DEVINL static __device__ __forceinline__
typedef __attribute__((ext_vector_type(8))) short short8;
typedef __attribute__((ext_vector_type(4))) float f32x4;

DEVINL float sigm(float x) { return 1.0f / (1.0f + __expf(-x)); }
DEVINL float tanh_fast(float x) { return 1.0f - 2.0f / (__expf(2.0f * x) + 1.0f); }
DEVINL float elu(float x) { return x > 0.0f ? x : expm1f(x); }
DEVINL unsigned short bf16_rne(float v) {
    unsigned u = __float_as_uint(v);
    unsigned r = (u + 0x7FFF + ((u >> 16) & 1)) >> 16;
    return (unsigned short)r;
}
DEVINL float bf16_to_f(unsigned short h) { return __uint_as_float(((unsigned)h) << 16); }

// ---------------- LSTM1 fused step (MFMA) ----------------
// grid (4,8,8) = (xq, y, b), block 512 = 8 waves; wave = M-tile m (16 gate-rows).
// A rows permuted so lane (l>>4) holds the 4 gates of channel f = m*4 + (l>>4)
// in its 4 C-regs (C/D map: col=lane&15, row=(lane>>4)*4+reg  [m89]).
// B staged x-major bf16 hi/lo: sB[lx][k], k = ci*3+dy (pad 99->128), XOR-swizzled.
// dx in {0,1,2} = 3 shifted GEMM passes over the same tile.
__global__ __launch_bounds__(512) void lstm1_step(
    const float* __restrict__ xin,          // (8,1,32,8,256)
    const unsigned short* __restrict__ wApk,// hi[3][128][128] then lo[3][128][128]
    const float* __restrict__ b1,           // (128)
    const float* __restrict__ hprev,        // (8,32,8,256)
    float* __restrict__ hout,               // (8,32,8,256)
    float* __restrict__ c1,                 // (8,32,8,256)
    int t)
{
    __shared__ __align__(16) unsigned short sBhi[66 * 128];
    __shared__ __align__(16) unsigned short sBlo[66 * 128];
    const int xq = blockIdx.x, y = blockIdx.y, b = blockIdx.z;
    const int x0 = xq * 64;
    const int tid = threadIdx.x;

    // stage input tile as bf16 hi/lo, swizzled: slot' = (k>>3) ^ (lx&15)
    for (int e = tid; e < 66 * 128; e += 512) {
        int lx = e % 66, kk = e / 66;
        float v = 0.0f;
        if (kk < 99) {
            int ci = kk / 3, dy = kk - ci * 3;
            int gy = y + dy - 1, gx = x0 + lx - 1;
            if (gy >= 0 && gy < 8 && gx >= 0 && gx < 256)
                v = (ci == 0) ? xin[((b * 32 + t) * 8 + gy) * 256 + gx]
                              : hprev[((b * 32 + (ci - 1)) * 8 + gy) * 256 + gx];
        }
        unsigned short hi = bf16_rne(v);
        unsigned short lo = bf16_rne(v - bf16_to_f(hi));
        int a16 = lx * 128 + (((kk >> 3) ^ (lx & 15)) << 3) + (kk & 7);
        sBhi[a16] = hi;
        sBlo[a16] = lo;
    }
    __syncthreads();

    const int l = tid & 63;
    const int m = __builtin_amdgcn_readfirstlane(tid >> 6); // M-tile, wave-uniform
    const int ln = l & 15, kg = l >> 4;
    f32x4 acc0 = {0.f, 0.f, 0.f, 0.f}, acc1 = acc0, acc2 = acc0, acc3 = acc0;
    const unsigned short* wAhi = wApk;
    const unsigned short* wAlo = wApk + 3 * 128 * 128;

#pragma unroll
    for (int dx = 0; dx < 3; ++dx) {
#pragma unroll
        for (int kk = 0; kk < 4; ++kk) {
            int aoff = (dx * 128 + m * 16 + ln) * 128 + kk * 32 + kg * 8;
            short8 ahi = *(const short8*)&wAhi[aoff];
            short8 alo = *(const short8*)&wAlo[aoff];
#pragma unroll
            for (int nt = 0; nt < 4; ++nt) {
                int lx = nt * 16 + ln + dx;
                int slot = kk * 4 + kg;
                int boff = lx * 128 + ((slot ^ (lx & 15)) << 3);
                short8 bhi = *(const short8*)&sBhi[boff];
                short8 blo = *(const short8*)&sBlo[boff];
                f32x4& a = (nt == 0) ? acc0 : (nt == 1) ? acc1 : (nt == 2) ? acc2 : acc3;
                a = __builtin_amdgcn_mfma_f32_16x16x32_bf16(alo, bhi, a, 0, 0, 0);
                a = __builtin_amdgcn_mfma_f32_16x16x32_bf16(ahi, blo, a, 0, 0, 0);
                a = __builtin_amdgcn_mfma_f32_16x16x32_bf16(ahi, bhi, a, 0, 0, 0);
            }
        }
    }

    // epilogue: lane holds (zi,zf,zg,zo) for channel f = m*4 + kg at 4 n-tiles
    const int f = m * 4 + kg;
    const float bi = b1[f], bff = b1[32 + f], bg = b1[64 + f], bo = b1[96 + f];
#pragma unroll
    for (int nt = 0; nt < 4; ++nt) {
        f32x4 a = (nt == 0) ? acc0 : (nt == 1) ? acc1 : (nt == 2) ? acc2 : acc3;
        int gidx = ((b * 32 + f) * 8 + y) * 256 + x0 + nt * 16 + ln;
        float zi = a[0] + bi, zf = a[1] + bff, zg = a[2] + bg, zo = a[3] + bo;
        float cv = c1[gidx];
        float cn = sigm(zf) * cv + sigm(zi) * tanh_fast(zg);
        c1[gidx] = cn;
        hout[gidx] = sigm(zo) * tanh_fast(cn);
    }
}

// ---------------- pool after LSTM1 (at odd t) ----------------
__global__ void pool1(const float* __restrict__ he, const float* __restrict__ ho,
                      float* __restrict__ p1, int tp)
{
    int idx = blockIdx.x * 256 + threadIdx.x;
    if (idx >= 8 * 32 * 4 * 128) return;
    int xp = idx & 127, t1 = idx >> 7;
    int yp = t1 & 3, t2 = t1 >> 2;
    int f = t2 & 31, b = t2 >> 5;
    int base = ((b * 32 + f) * 8 + yp * 2) * 256 + xp * 2;
    float m = he[base];
    m = fmaxf(m, he[base + 1]);
    m = fmaxf(m, he[base + 256]);
    m = fmaxf(m, he[base + 257]);
    m = fmaxf(m, ho[base]);
    m = fmaxf(m, ho[base + 1]);
    m = fmaxf(m, ho[base + 256]);
    m = fmaxf(m, ho[base + 257]);
    p1[(((b * 32 + f) * 16 + tp) * 4 + yp) * 128 + xp] = m;
}

// ---------------- LSTM2: z = conv(concat(xt,h)) (fp32, unchanged) ----------------
__global__ __launch_bounds__(512) void lstm2_z(
    const float* __restrict__ p1,    // (8,32,16,4,128)
    const float* __restrict__ w2G,   // (32,240,18)
    const float* __restrict__ b2,    // (192)
    const float* __restrict__ hprev, // (8,48,4,128)
    float* __restrict__ z2,          // (8,192,4,128)
    int t)
{
    __shared__ float sIn[80 * 3 * 66];
    const int bx = blockIdx.x, y = blockIdx.y, b = blockIdx.z;
    const int xh = bx & 1, cq = bx >> 1;
    const int x0 = xh * 64;
    const int tid = threadIdx.x;

    for (int idx = tid; idx < 80 * 198; idx += 512) {
        int ci = idx / 198, rem = idx % 198;
        int dy = rem / 66, lx = rem % 66;
        int gy = y + dy - 1, gx = x0 + lx - 1;
        float v = 0.0f;
        if (gy >= 0 && gy < 4 && gx >= 0 && gx < 128) {
            v = (ci < 32) ? p1[(((b * 32 + ci) * 16 + t) * 4 + gy) * 128 + gx]
                          : hprev[((b * 48 + (ci - 32)) * 4 + gy) * 128 + gx];
        }
        sIn[idx] = v;
    }
    __syncthreads();

    const int p = tid & 63;
    const int cg = __builtin_amdgcn_readfirstlane(tid >> 6);
    const int g = cq * 8 + cg;           // 0..31
    const float* wbase = w2G + g * 4320;
    const int co0 = g * 6;
    float acc[6];
#pragma unroll
    for (int j = 0; j < 6; ++j) acc[j] = b2[co0 + j];

    for (int ci = 0; ci < 80; ++ci) {
        const float* sr = &sIn[ci * 198 + p];
        const float* wk = wbase + ci * 54;
#pragma unroll
        for (int dy = 0; dy < 3; ++dy) {
            float v0 = sr[dy * 66], v1 = sr[dy * 66 + 1], v2 = sr[dy * 66 + 2];
            const float* w0 = wk + dy * 18;
#pragma unroll
            for (int j = 0; j < 6; ++j)
                acc[j] = fmaf(v2, w0[12 + j],
                         fmaf(v1, w0[6 + j],
                         fmaf(v0, w0[j], acc[j])));
        }
    }
    const int gx = x0 + p;
#pragma unroll
    for (int j = 0; j < 6; ++j)
        z2[((b * 192 + co0 + j) * 4 + y) * 128 + gx] = acc[j];
}

// ---------------- LSTM2 gates + fused pool (at odd t) ----------------
__global__ void lstm2_gate(const float* __restrict__ z2, float* __restrict__ c2,
                           const float* __restrict__ hprevpool,
                           float* __restrict__ hout, float* __restrict__ p2, int t)
{
    int idx = blockIdx.x * 256 + threadIdx.x;
    if (idx >= 8 * 48 * 2 * 64) return;
    int xp = idx & 63; int t1 = idx >> 6;
    int yp = t1 & 1; t1 >>= 1;
    int f = t1 % 48; int b = t1 / 48;
    float m = -INFINITY;
#pragma unroll
    for (int dy = 0; dy < 2; ++dy) {
#pragma unroll
        for (int dx = 0; dx < 2; ++dx) {
            int y = yp * 2 + dy, xx = xp * 2 + dx;
            int zbase = ((b * 192 + f) * 4 + y) * 128 + xx;
            float zi = z2[zbase];
            float zf = z2[zbase + 48 * 512];
            float zg = z2[zbase + 96 * 512];
            float zo = z2[zbase + 144 * 512];
            int gidx = ((b * 48 + f) * 4 + y) * 128 + xx;
            float cv = c2[gidx];
            float cn = sigm(zf) * cv + sigm(zi) * tanh_fast(zg);
            float hn = sigm(zo) * tanh_fast(cn);
            c2[gidx] = cn;
            hout[gidx] = hn;
            m = fmaxf(m, hn);
            if (t & 1) m = fmaxf(m, hprevpool[gidx]);
        }
    }
    if (t & 1) {
        int tp = t >> 1;
        p2[(((b * 48 + f) * 8 + tp) * 2 + yp) * 64 + xp] = m;
    }
}

// ---------------- conv3 (K-split partials) ----------------
__global__ __launch_bounds__(256) void conv3_part(
    const float* __restrict__ in3,  // (8,48,16,64)
    const float* __restrict__ w3T,  // (9216,256)
    float* __restrict__ part)       // (16,8,256,14)
{
    __shared__ float sIn[3 * 16 * 64];
    const int nh = blockIdx.x, kq = blockIdx.y, b = blockIdx.z;
    const int tid = threadIdx.x;
    const int c0 = kq * 3;
    for (int idx = tid; idx < 3 * 16 * 64; idx += 256) {
        int w = idx & 63, t1 = idx >> 6;
        int r = t1 & 15, cl = t1 >> 4;
        sIn[idx] = in3[((b * 48 + c0 + cl) * 16 + r) * 64 + w];
    }
    __syncthreads();
    const int n = nh * 128 + (tid & 127);
    const int rh = tid >> 7;
    float acc[7];
#pragma unroll
    for (int r = 0; r < 7; ++r) acc[r] = 0.0f;
    for (int cl = 0; cl < 3; ++cl)
        for (int dr = 0; dr < 3; ++dr)
            for (int w = 0; w < 64; ++w) {
                int k = ((c0 + cl) * 3 + dr) * 64 + w;
                float wt = w3T[k * 256 + n];
                const float* ip = &sIn[(cl * 16 + dr + rh * 7) * 64 + w];
#pragma unroll
                for (int r = 0; r < 7; ++r)
                    acc[r] = fmaf(ip[r * 64], wt, acc[r]);
            }
    float* pp = &part[((kq * 8 + b) * 256 + n) * 14 + rh * 7];
#pragma unroll
    for (int r = 0; r < 7; ++r) pp[r] = acc[r];
}

__global__ void conv3_reduce(const float* __restrict__ part,
                             const float* __restrict__ b3, float* __restrict__ out3)
{
    int idx = blockIdx.x * 256 + threadIdx.x;
    if (idx >= 8 * 256 * 14) return;
    int r = idx % 14, t1 = idx / 14;
    int n = t1 & 255, b = t1 >> 8;
    float s = b3[n];
#pragma unroll
    for (int kq = 0; kq < 16; ++kq)
        s += part[((kq * 8 + b) * 256 + n) * 14 + r];
    out3[idx] = elu(s);   // (8,256,14)
}

// ---------------- conv4 (1x1, 256->128) + ELU ----------------
__global__ __launch_bounds__(128) void conv4(
    const float* __restrict__ out3, const float* __restrict__ w4T,
    const float* __restrict__ b4, float* __restrict__ out4)
{
    const int r = blockIdx.x, b = blockIdx.y, n = threadIdx.x;
    float acc = b4[n];
    for (int cc = 0; cc < 256; ++cc)
        acc = fmaf(out3[(b * 256 + cc) * 14 + r], w4T[cc * 128 + n], acc);
    out4[(b * 128 + n) * 14 + r] = elu(acc); // (8,128,14)
}

// ---------------- conv5 (1x1, 128->88) ----------------
__global__ __launch_bounds__(128) void conv5(
    const float* __restrict__ out4, const float* __restrict__ w5T,
    const float* __restrict__ b5, float* __restrict__ outp)
{
    const int r = blockIdx.x, b = blockIdx.y, n = threadIdx.x;
    if (n >= 88) return;
    float acc = b5[n];
    for (int cc = 0; cc < 128; ++cc)
        acc = fmaf(out4[(b * 128 + cc) * 14 + r], w5T[cc * 88 + n], acc);
    outp[(b * 88 + n) * 14 + r] = acc; // (8,88,14,1)
}

// ---------------- weight re-layouts ----------------
// wApk: hi[3][128][128] ++ lo[3][128][128] bf16; row = (f>>2)*16+(f&3)*4+gate,
//       co = gate*32+f; k = ci*3+dy (pad 99..127 = 0)
// w2G[g][kk][dx*6+j] (32,240,18); w3T (9216,256); w4T (256,128); w5T (128,88)
__global__ void prep(const float* __restrict__ w1, const float* __restrict__ w2,
                     const float* __restrict__ w3, const float* __restrict__ w4,
                     const float* __restrict__ w5, unsigned short* __restrict__ wApk,
                     float* __restrict__ w2G, float* __restrict__ w3T,
                     float* __restrict__ w4T, float* __restrict__ w5T)
{
    int idx = blockIdx.x * 256 + threadIdx.x;
    if (idx < 49152) {                          // wApk (3*128*128), hi+lo
        int dx = idx / 16384, rem = idx % 16384;
        int row = rem / 128, k = rem % 128;
        int mt = row >> 4, q = (row >> 2) & 3, gate = row & 3;
        int f = mt * 4 + q, co = gate * 32 + f;
        float v = 0.0f;
        if (k < 99) {
            int ci = k / 3, dy = k - ci * 3;
            v = w1[co * 297 + ci * 9 + dy * 3 + dx];
        }
        unsigned short hi = bf16_rne(v);
        wApk[idx] = hi;
        wApk[49152 + idx] = bf16_rne(v - bf16_to_f(hi));
        return;
    }
    idx -= 49152;
    if (idx < 138240) {                         // w2G
        int g = idx / 4320, rem = idx % 4320;
        int kk = rem / 18, dd = rem % 18;
        int dx = dd / 6, j = dd % 6;
        int ci = kk / 3, dy = kk % 3;
        int co = g * 6 + j;
        w2G[idx] = w2[co * 720 + ci * 9 + dy * 3 + dx];
        return;
    }
    idx -= 138240;
    if (idx < 2359296) {                        // w3 (256,9216) -> (9216,256)
        int n = idx / 9216, k = idx % 9216;
        w3T[k * 256 + n] = w3[idx];
        return;
    }
    idx -= 2359296;
    if (idx < 32768) {                          // w4 (128,256) -> (256,128)
        int n = idx / 256, c = idx % 256;
        w4T[c * 128 + n] = w4[idx];
        return;
    }
    idx -= 32768;
    if (idx < 11264) {                          // w5 (88,128) -> (128,88)
        int n = idx / 128, c = idx % 128;
        w5T[c * 88 + n] = w5[idx];
    }
}

extern "C" void kernel_launch(void* const* d_in, const int* in_sizes, int n_in,
                              void* d_out, int out_size, void* d_ws, size_t ws_size,
                              hipStream_t stream)
{
    const float* x  = (const float*)d_in[0];
    const float* w1 = (const float*)d_in[1];
    const float* b1 = (const float*)d_in[2];
    const float* w2 = (const float*)d_in[3];
    const float* b2 = (const float*)d_in[4];
    const float* w3 = (const float*)d_in[5];
    const float* b3 = (const float*)d_in[6];
    const float* w4 = (const float*)d_in[7];
    const float* b4 = (const float*)d_in[8];
    const float* w5 = (const float*)d_in[9];
    const float* b5 = (const float*)d_in[10];
    float* out = (float*)d_out;

    float* ws = (float*)d_ws;
    size_t off = 0;
    auto alloc = [&](size_t n) { float* p = ws + off; off += n; return p; };
    float* h1[2]; h1[0] = alloc(524288); h1[1] = alloc(524288); // (8,32,8,256)
    float* c1 = alloc(524288);
    float* p1 = alloc(2097152);  // (8,32,16,4,128)
    float* h2[2]; h2[0] = alloc(196608); h2[1] = alloc(196608); // (8,48,4,128)
    float* c2 = alloc(196608);
    float* z2 = alloc(786432);   // (8,192,4,128)
    float* p2 = alloc(393216);   // (8,48,16,64)
    float* part3 = alloc(458752);// (16,8,256,14)
    float* out3 = alloc(28672);  // (8,256,14)
    float* out4 = alloc(14336);  // (8,128,14)
    unsigned short* wApk = (unsigned short*)alloc(49152); // 98304 bf16 (hi+lo)
    float* w2G = alloc(138240);
    float* w3T = alloc(2359296);
    float* w4T = alloc(32768);
    float* w5T = alloc(11264);
    (void)ws_size; (void)off;

    hipMemsetAsync(h1[1], 0, 524288 * sizeof(float), stream);
    hipMemsetAsync(c1,    0, 524288 * sizeof(float), stream);
    hipMemsetAsync(h2[1], 0, 196608 * sizeof(float), stream);
    hipMemsetAsync(c2,    0, 196608 * sizeof(float), stream);

    prep<<<10120, 256, 0, stream>>>(w1, w2, w3, w4, w5, wApk, w2G, w3T, w4T, w5T);

    for (int t = 0; t < 32; ++t) {
        lstm1_step<<<dim3(4, 8, 8), 512, 0, stream>>>(
            x, wApk, b1, h1[1 - (t & 1)], h1[t & 1], c1, t);
        if (t & 1)
            pool1<<<512, 256, 0, stream>>>(h1[0], h1[1], p1, t >> 1);
    }
    for (int t = 0; t < 16; ++t) {
        lstm2_z<<<dim3(8, 4, 8), 512, 0, stream>>>(
            p1, w2G, b2, h2[1 - (t & 1)], z2, t);
        lstm2_gate<<<192, 256, 0, stream>>>(
            z2, c2, h2[1 - (t & 1)], h2[t & 1], p2, t);
    }
    conv3_part<<<dim3(2, 16, 8), 256, 0, stream>>>(p2, w3T, part3);
    conv3_reduce<<<112, 256, 0, stream>>>(part3, b3, out3);
    conv4<<<dim3(14, 8), 128, 0, stream>>>(out3, w4T, b4, out4);
    conv5<<<dim3(14, 8), 128, 0, stream>>>(out4, w5T, b5, out);
}

// Round 4
// 776.011 us; speedup vs baseline: 3.0899x; 1.5541x over previous
//
#include <hip/hip_runtime.h>
#include <math.h>

// Net: ConvLSTM(32)->pool->ConvLSTM(48)->pool->conv3+ELU->conv4(1x1)+ELU->conv5(1x1)
// B=8, T=32, H=8, W=256, F1=32, F2=48, F3=256, F4=128, NNOTE=88
// R4: everything matmul-shaped on MFMA (split-bf16 3-term). Fragment-linear
//     weight prepacks (coalesced A loads). lstm2 gates fused in-register.
//     conv3 streams B from global with zero overfetch. pool1 fused into lstm1.

#define DEVINL static __device__ __forceinline__
typedef __attribute__((ext_vector_type(8))) short short8;
typedef __attribute__((ext_vector_type(4))) float f32x4;

#define PLANE_W1 49152      // w1F elements per plane (3*8*4*4*16*8)
#define PLANE_W2 147456     // w2F (3*12*8*4*16*8)
#define PLANE_W3 2359296    // w3F (16*48*6*4*16*8)

DEVINL float sigm(float x) { return 1.0f / (1.0f + __expf(-x)); }
DEVINL float tanh_fast(float x) { return 1.0f - 2.0f / (__expf(2.0f * x) + 1.0f); }
DEVINL float elu(float x) { return x > 0.0f ? x : expm1f(x); }
DEVINL unsigned short bf16_rne(float v) {
    unsigned u = __float_as_uint(v);
    unsigned r = (u + 0x7FFF + ((u >> 16) & 1)) >> 16;
    return (unsigned short)r;
}
DEVINL float bf16_to_f(unsigned short h) { return __uint_as_float(((unsigned)h) << 16); }

// ---------------- LSTM1 fused step (MFMA) ----------------
// grid (4,8,8) = (xq, y, b), block 512 = 8 waves; wave = M-tile m.
// A-frag: lane(ln,kg) row=m*16+ln, k=kk*32+kg*8 (w1F fragment-linear).
// C/D: col=lane&15, row=kg*4+reg -> lane holds gates i/f/g/o of f=m*4+kg.
// At even t>=2, odd-y blocks also pool pair (t-2,t-1) into p1 (bf16 hi/lo).
__global__ __launch_bounds__(512) void lstm1_step(
    const float* __restrict__ xin,           // (8,1,32,8,256)
    const unsigned short* __restrict__ w1F,  // hi plane + lo plane
    const float* __restrict__ b1,            // (128)
    const float* __restrict__ hprev,         // h1[(t+2)%3]
    const float* __restrict__ hpoolA,        // h1[(t+1)%3] = t-2's h
    float* __restrict__ hout,                // h1[t%3]
    float* __restrict__ c1,                  // (8,32,8,256)
    unsigned short* __restrict__ p1hi, unsigned short* __restrict__ p1lo,
    int t)
{
    __shared__ __align__(16) unsigned short sBhi[66 * 128];
    __shared__ __align__(16) unsigned short sBlo[66 * 128];
    const int xq = blockIdx.x, y = blockIdx.y, b = blockIdx.z;
    const int x0 = xq * 64;
    const int tid = threadIdx.x;

    // fused pool of pair (t-2, t-1) -> p1[tp], done by odd-y blocks
    if (((t & 1) == 0) && t >= 2 && (y & 1) == 1) {
        int tp = (t >> 1) - 1, yp = y >> 1;
        for (int e = tid; e < 1024; e += 512) {
            int f = e >> 5, xl = e & 31;
            int xp = (x0 >> 1) + xl, gx = x0 + 2 * xl;
            int b0 = ((b * 32 + f) * 8 + (y - 1)) * 256 + gx;
            float m = hpoolA[b0];
            m = fmaxf(m, hpoolA[b0 + 1]);
            m = fmaxf(m, hpoolA[b0 + 256]);
            m = fmaxf(m, hpoolA[b0 + 257]);
            m = fmaxf(m, hprev[b0]);
            m = fmaxf(m, hprev[b0 + 1]);
            m = fmaxf(m, hprev[b0 + 256]);
            m = fmaxf(m, hprev[b0 + 257]);
            int pi = (((b * 32 + f) * 16 + tp) * 4 + yp) * 128 + xp;
            unsigned short hi = bf16_rne(m);
            p1hi[pi] = hi;
            p1lo[pi] = bf16_rne(m - bf16_to_f(hi));
        }
    }

    // stage input tile as bf16 hi/lo, swizzled: slot' = (k>>3) ^ (lx&15)
    for (int e = tid; e < 66 * 128; e += 512) {
        int lx = e % 66, kk = e / 66;
        float v = 0.0f;
        if (kk < 99) {
            int ci = kk / 3, dy = kk - ci * 3;
            int gy = y + dy - 1, gx = x0 + lx - 1;
            if (gy >= 0 && gy < 8 && gx >= 0 && gx < 256)
                v = (ci == 0) ? xin[((b * 32 + t) * 8 + gy) * 256 + gx]
                              : hprev[((b * 32 + (ci - 1)) * 8 + gy) * 256 + gx];
        }
        unsigned short hi = bf16_rne(v);
        unsigned short lo = bf16_rne(v - bf16_to_f(hi));
        int a16 = lx * 128 + (((kk >> 3) ^ (lx & 15)) << 3) + (kk & 7);
        sBhi[a16] = hi;
        sBlo[a16] = lo;
    }
    __syncthreads();

    const int l = tid & 63;
    const int m = __builtin_amdgcn_readfirstlane(tid >> 6);
    const int ln = l & 15, kg = l >> 4;
    f32x4 acc0 = {0.f, 0.f, 0.f, 0.f}, acc1 = acc0, acc2 = acc0, acc3 = acc0;

#pragma unroll
    for (int dx = 0; dx < 3; ++dx) {
#pragma unroll
        for (int kk = 0; kk < 4; ++kk) {
            int aoff = ((((dx * 8 + m) * 4 + kk) * 4 + kg) * 16 + ln) * 8;
            short8 ahi = *(const short8*)&w1F[aoff];
            short8 alo = *(const short8*)&w1F[PLANE_W1 + aoff];
#pragma unroll
            for (int nt = 0; nt < 4; ++nt) {
                int lx = nt * 16 + ln + dx;
                int slot = kk * 4 + kg;
                int boff = lx * 128 + ((slot ^ (lx & 15)) << 3);
                short8 bhi = *(const short8*)&sBhi[boff];
                short8 blo = *(const short8*)&sBlo[boff];
                f32x4& a = (nt == 0) ? acc0 : (nt == 1) ? acc1 : (nt == 2) ? acc2 : acc3;
                a = __builtin_amdgcn_mfma_f32_16x16x32_bf16(alo, bhi, a, 0, 0, 0);
                a = __builtin_amdgcn_mfma_f32_16x16x32_bf16(ahi, blo, a, 0, 0, 0);
                a = __builtin_amdgcn_mfma_f32_16x16x32_bf16(ahi, bhi, a, 0, 0, 0);
            }
        }
    }

    const int f = m * 4 + kg;
    const float bi = b1[f], bff = b1[32 + f], bg = b1[64 + f], bo = b1[96 + f];
#pragma unroll
    for (int nt = 0; nt < 4; ++nt) {
        f32x4 a = (nt == 0) ? acc0 : (nt == 1) ? acc1 : (nt == 2) ? acc2 : acc3;
        int gidx = ((b * 32 + f) * 8 + y) * 256 + x0 + nt * 16 + ln;
        float zi = a[0] + bi, zf = a[1] + bff, zg = a[2] + bg, zo = a[3] + bo;
        float cv = c1[gidx];
        float cn = sigm(zf) * cv + sigm(zi) * tanh_fast(zg);
        c1[gidx] = cn;
        hout[gidx] = sigm(zo) * tanh_fast(cn);
    }
}

// ---------------- final pool1 for tp=15 ----------------
__global__ void pool1k(const float* __restrict__ hA, const float* __restrict__ hB,
                       unsigned short* __restrict__ p1hi, unsigned short* __restrict__ p1lo,
                       int tp)
{
    int idx = blockIdx.x * 256 + threadIdx.x;
    if (idx >= 8 * 32 * 4 * 128) return;
    int xp = idx & 127, t1 = idx >> 7;
    int yp = t1 & 3, t2 = t1 >> 2;
    int f = t2 & 31, b = t2 >> 5;
    int base = ((b * 32 + f) * 8 + yp * 2) * 256 + xp * 2;
    float m = hA[base];
    m = fmaxf(m, hA[base + 1]);
    m = fmaxf(m, hA[base + 256]);
    m = fmaxf(m, hA[base + 257]);
    m = fmaxf(m, hB[base]);
    m = fmaxf(m, hB[base + 1]);
    m = fmaxf(m, hB[base + 256]);
    m = fmaxf(m, hB[base + 257]);
    int pi = (((b * 32 + f) * 16 + tp) * 4 + yp) * 128 + xp;
    unsigned short hi = bf16_rne(m);
    p1hi[pi] = hi;
    p1lo[pi] = bf16_rne(m - bf16_to_f(hi));
}

// ---------------- LSTM2 step (MFMA, gates fused) ----------------
// grid (8,4,8) = (xq, y, b), block 256 = 4 waves; wave wv owns mt = wv*3..wv*3+2.
// M=192 perm rows: row = (f>>2)*16 + (f&3)*4 + gate, co = gate*48+f.
// B staged [lx 0..17][k 0..255] (k=ci*3+dy, 240 used), XOR-swizzled.
__global__ __launch_bounds__(256) void lstm2_step(
    const unsigned short* __restrict__ p1hi, const unsigned short* __restrict__ p1lo,
    const unsigned short* __restrict__ w2F,  // hi plane + lo plane
    const float* __restrict__ b2,            // (192)
    const float* __restrict__ hprev,         // (8,48,4,128)
    float* __restrict__ c2,                  // (8,48,4,128)
    float* __restrict__ hout,                // (8,48,4,128)
    int t)
{
    __shared__ __align__(16) unsigned short sBhi[18 * 256];
    __shared__ __align__(16) unsigned short sBlo[18 * 256];
    const int xq = blockIdx.x, y = blockIdx.y, b = blockIdx.z;
    const int x0 = xq * 16;
    const int tid = threadIdx.x;

    for (int idx = tid; idx < 80 * 54; idx += 256) {
        int ci = idx / 54, rem = idx % 54;
        int dy = rem / 18, lx = rem % 18;
        int gy = y + dy - 1, gx = x0 + lx - 1;
        unsigned short hi = 0, lo = 0;
        if (gy >= 0 && gy < 4 && gx >= 0 && gx < 128) {
            if (ci < 32) {
                int pi = (((b * 32 + ci) * 16 + t) * 4 + gy) * 128 + gx;
                hi = p1hi[pi];
                lo = p1lo[pi];
            } else {
                float v = hprev[((b * 48 + (ci - 32)) * 4 + gy) * 128 + gx];
                hi = bf16_rne(v);
                lo = bf16_rne(v - bf16_to_f(hi));
            }
        }
        int k = ci * 3 + dy;
        int a16 = lx * 256 + (((k >> 3) ^ (lx & 15)) << 3) + (k & 7);
        sBhi[a16] = hi;
        sBlo[a16] = lo;
    }
    // zero pad slots (k = 240..255)
    for (int e = tid; e < 18 * 16; e += 256) {
        int lx = e >> 4, k = 240 + (e & 15);
        int a16 = lx * 256 + (((k >> 3) ^ (lx & 15)) << 3) + (k & 7);
        sBhi[a16] = 0;
        sBlo[a16] = 0;
    }
    __syncthreads();

    const int l = tid & 63;
    const int wv = __builtin_amdgcn_readfirstlane(tid >> 6);
    const int ln = l & 15, kg = l >> 4;
    f32x4 acc[3] = {{0.f, 0.f, 0.f, 0.f}, {0.f, 0.f, 0.f, 0.f}, {0.f, 0.f, 0.f, 0.f}};

#pragma unroll
    for (int kk = 0; kk < 8; ++kk) {
        short8 bh[3], bl[3];
#pragma unroll
        for (int dx = 0; dx < 3; ++dx) {
            int lx = ln + dx;
            int boff = lx * 256 + ((((kk << 2) + kg) ^ (lx & 15)) << 3);
            bh[dx] = *(const short8*)&sBhi[boff];
            bl[dx] = *(const short8*)&sBlo[boff];
        }
#pragma unroll
        for (int j = 0; j < 3; ++j) {
            int mt = wv * 3 + j;
#pragma unroll
            for (int dx = 0; dx < 3; ++dx) {
                int aoff = ((((dx * 12 + mt) * 8 + kk) * 4 + kg) * 16 + ln) * 8;
                short8 ah = *(const short8*)&w2F[aoff];
                short8 al = *(const short8*)&w2F[PLANE_W2 + aoff];
                acc[j] = __builtin_amdgcn_mfma_f32_16x16x32_bf16(al, bh[dx], acc[j], 0, 0, 0);
                acc[j] = __builtin_amdgcn_mfma_f32_16x16x32_bf16(ah, bl[dx], acc[j], 0, 0, 0);
                acc[j] = __builtin_amdgcn_mfma_f32_16x16x32_bf16(ah, bh[dx], acc[j], 0, 0, 0);
            }
        }
    }

    const int x = x0 + ln;
#pragma unroll
    for (int j = 0; j < 3; ++j) {
        int mt = wv * 3 + j;
        int f = mt * 4 + kg;
        float zi = acc[j][0] + b2[f];
        float zf = acc[j][1] + b2[48 + f];
        float zg = acc[j][2] + b2[96 + f];
        float zo = acc[j][3] + b2[144 + f];
        int gidx = ((b * 48 + f) * 4 + y) * 128 + x;
        float cv = c2[gidx];
        float cn = sigm(zf) * cv + sigm(zi) * tanh_fast(zg);
        c2[gidx] = cn;
        hout[gidx] = sigm(zo) * tanh_fast(cn);
    }
}

// ---------------- pool2 (odd t): h2 pair -> p2 bf16 hi/lo planes ----------------
__global__ void pool2(const float* __restrict__ hA, const float* __restrict__ hB,
                      unsigned short* __restrict__ p2hi, unsigned short* __restrict__ p2lo,
                      int tp)
{
    int idx = blockIdx.x * 256 + threadIdx.x;
    if (idx >= 8 * 48 * 2 * 64) return;
    int xp = idx & 63;
    int t1 = idx >> 6;
    int yp = t1 & 1; t1 >>= 1;
    int f = t1 % 48, b = t1 / 48;
    float m = -INFINITY;
#pragma unroll
    for (int dy = 0; dy < 2; ++dy)
#pragma unroll
        for (int dx = 0; dx < 2; ++dx) {
            int g = ((b * 48 + f) * 4 + yp * 2 + dy) * 128 + xp * 2 + dx;
            m = fmaxf(m, fmaxf(hA[g], hB[g]));
        }
    int pi = ((b * 48 + f) * 16 + tp * 2 + yp) * 64 + xp;
    unsigned short hi = bf16_rne(m);
    p2hi[pi] = hi;
    p2lo[pi] = bf16_rne(m - bf16_to_f(hi));
}

// ---------------- conv3 (streaming MFMA, K-split partials) ----------------
// grid (16 mq, 12 ck), block 256 = 4 waves; wave wv -> c = ck*4+wv.
// A = w3F fragment-linear; B = p2 planes, short8 loads with zero overfetch.
__global__ __launch_bounds__(256) void conv3_part(
    const unsigned short* __restrict__ p2hi, const unsigned short* __restrict__ p2lo,
    const unsigned short* __restrict__ w3F,
    float* __restrict__ part)    // (12,256,112)
{
    __shared__ float sRed[4 * 7 * 256];
    const int mq = blockIdx.x, ck = blockIdx.y;
    const int tid = threadIdx.x;
    const int l = tid & 63;
    const int wv = __builtin_amdgcn_readfirstlane(tid >> 6);
    const int c = ck * 4 + wv;
    const int ln = l & 15, kg = l >> 4;

    int rowbase[7];
#pragma unroll
    for (int nt = 0; nt < 7; ++nt) {
        int col = nt * 16 + ln;
        int bi = col / 14, r = col % 14;
        rowbase[nt] = (bi * 48 + c) * 16 + r;
    }

    f32x4 acc[7];
#pragma unroll
    for (int nt = 0; nt < 7; ++nt) acc[nt] = (f32x4){0.f, 0.f, 0.f, 0.f};

#pragma unroll
    for (int kk = 0; kk < 6; ++kk) {
        int aoff = ((((mq * 48 + c) * 6 + kk) * 4 + kg) * 16 + ln) * 8;
        short8 ah = *(const short8*)&w3F[aoff];
        short8 al = *(const short8*)&w3F[PLANE_W3 + aoff];
        int s = kk * 4 + kg;
        int dr = s >> 3, w0 = (s & 7) * 8;
#pragma unroll
        for (int nt = 0; nt < 7; ++nt) {
            int boff = (rowbase[nt] + dr) * 64 + w0;
            short8 bh = *(const short8*)&p2hi[boff];
            short8 bl = *(const short8*)&p2lo[boff];
            acc[nt] = __builtin_amdgcn_mfma_f32_16x16x32_bf16(al, bh, acc[nt], 0, 0, 0);
            acc[nt] = __builtin_amdgcn_mfma_f32_16x16x32_bf16(ah, bl, acc[nt], 0, 0, 0);
            acc[nt] = __builtin_amdgcn_mfma_f32_16x16x32_bf16(ah, bh, acc[nt], 0, 0, 0);
        }
    }

#pragma unroll
    for (int nt = 0; nt < 7; ++nt)
        *(f32x4*)&sRed[wv * 1792 + nt * 256 + l * 4] = acc[nt];
    __syncthreads();

#pragma unroll
    for (int nt = 0; nt < 7; ++nt) {
        float s = sRed[nt * 256 + tid] + sRed[1792 + nt * 256 + tid] +
                  sRed[2 * 1792 + nt * 256 + tid] + sRed[3 * 1792 + nt * 256 + tid];
        int r16 = (tid >> 6) * 4 + (tid & 3);
        int m = mq * 16 + r16;
        int col = nt * 16 + ((tid >> 2) & 15);
        part[(ck * 256 + m) * 112 + col] = s;
    }
}

// ---------------- head: reduce+bias+ELU -> conv4+ELU -> conv5 ----------------
// grid 112 = (b*14+r), block 256.
__global__ __launch_bounds__(256) void head(
    const float* __restrict__ part, const float* __restrict__ b3,
    const float* __restrict__ w4T, const float* __restrict__ b4,
    const float* __restrict__ w5T, const float* __restrict__ b5,
    float* __restrict__ out)
{
    __shared__ float sO3[256];
    __shared__ float sO4[128];
    const int col = blockIdx.x;          // b*14 + r
    const int b = col / 14, r = col % 14;
    const int tid = threadIdx.x;

    float s = b3[tid];
#pragma unroll
    for (int ck = 0; ck < 12; ++ck)
        s += part[(ck * 256 + tid) * 112 + col];
    sO3[tid] = elu(s);
    __syncthreads();

    if (tid < 128) {
        float a4 = b4[tid];
        for (int c = 0; c < 256; ++c)
            a4 = fmaf(sO3[c], w4T[c * 128 + tid], a4);
        sO4[tid] = elu(a4);
    }
    __syncthreads();

    if (tid < 88) {
        float a5 = b5[tid];
        for (int c = 0; c < 128; ++c)
            a5 = fmaf(sO4[c], w5T[c * 88 + tid], a5);
        out[(b * 88 + tid) * 14 + r] = a5;
    }
}

// ---------------- weight prepacks (fragment-linear, bf16 hi/lo) ----------------
__global__ void prep(const float* __restrict__ w1, const float* __restrict__ w2,
                     const float* __restrict__ w3, const float* __restrict__ w4,
                     const float* __restrict__ w5,
                     unsigned short* __restrict__ w1F, unsigned short* __restrict__ w2F,
                     unsigned short* __restrict__ w3F,
                     float* __restrict__ w4T, float* __restrict__ w5T)
{
    int idx = blockIdx.x * 256 + threadIdx.x;
    if (idx < PLANE_W1) {   // w1F[dx][mt 8][kk 4][kg][ln][8]
        int dx = idx / 16384, rem = idx % 16384;
        int mt = rem / 2048, r2 = rem % 2048;
        int kk = r2 / 512, r3 = r2 % 512;
        int kg = r3 / 128, r4 = r3 % 128;
        int ln = r4 / 8, e = r4 % 8;
        int f = mt * 4 + (ln >> 2), gate = ln & 3;
        int co = gate * 32 + f;
        int k = kk * 32 + kg * 8 + e;
        float v = 0.0f;
        if (k < 99) v = w1[co * 297 + (k / 3) * 9 + (k % 3) * 3 + dx];
        unsigned short hi = bf16_rne(v);
        w1F[idx] = hi;
        w1F[PLANE_W1 + idx] = bf16_rne(v - bf16_to_f(hi));
        return;
    }
    idx -= PLANE_W1;
    if (idx < PLANE_W2) {   // w2F[dx][mt 12][kk 8][kg][ln][8]
        int dx = idx / 49152, rem = idx % 49152;
        int mt = rem / 4096, r2 = rem % 4096;
        int kk = r2 / 512, r3 = r2 % 512;
        int kg = r3 / 128, r4 = r3 % 128;
        int ln = r4 / 8, e = r4 % 8;
        int f = mt * 4 + (ln >> 2), gate = ln & 3;
        int co = gate * 48 + f;
        int k = kk * 32 + kg * 8 + e;
        float v = 0.0f;
        if (k < 240) v = w2[co * 720 + (k / 3) * 9 + (k % 3) * 3 + dx];
        unsigned short hi = bf16_rne(v);
        w2F[idx] = hi;
        w2F[PLANE_W2 + idx] = bf16_rne(v - bf16_to_f(hi));
        return;
    }
    idx -= PLANE_W2;
    if (idx < PLANE_W3) {   // w3F[mq 16][c 48][kk 6][kg][ln][8]
        int mq = idx / 147456, rem = idx % 147456;
        int c = rem / 3072, r2 = rem % 3072;
        int kk = r2 / 512, r3 = r2 % 512;
        int kg = r3 / 128, r4 = r3 % 128;
        int ln = r4 / 8, e = r4 % 8;
        int m = mq * 16 + ln;
        int kc = kk * 32 + kg * 8 + e;
        int dr = kc >> 6, w = kc & 63;
        float v = w3[((m * 48 + c) * 3 + dr) * 64 + w];
        unsigned short hi = bf16_rne(v);
        w3F[idx] = hi;
        w3F[PLANE_W3 + idx] = bf16_rne(v - bf16_to_f(hi));
        return;
    }
    idx -= PLANE_W3;
    if (idx < 32768) {      // w4 (128,256) -> w4T (256,128)
        int n = idx / 256, cch = idx % 256;
        w4T[cch * 128 + n] = w4[idx];
        return;
    }
    idx -= 32768;
    if (idx < 11264) {      // w5 (88,128) -> w5T (128,88)
        int n = idx / 128, cch = idx % 128;
        w5T[cch * 88 + n] = w5[idx];
    }
}

extern "C" void kernel_launch(void* const* d_in, const int* in_sizes, int n_in,
                              void* d_out, int out_size, void* d_ws, size_t ws_size,
                              hipStream_t stream)
{
    const float* x  = (const float*)d_in[0];
    const float* w1 = (const float*)d_in[1];
    const float* b1 = (const float*)d_in[2];
    const float* w2 = (const float*)d_in[3];
    const float* b2 = (const float*)d_in[4];
    const float* w3 = (const float*)d_in[5];
    const float* b3 = (const float*)d_in[6];
    const float* w4 = (const float*)d_in[7];
    const float* b4 = (const float*)d_in[8];
    const float* w5 = (const float*)d_in[9];
    const float* b5 = (const float*)d_in[10];
    float* out = (float*)d_out;

    float* ws = (float*)d_ws;
    size_t off = 0;
    auto alloc = [&](size_t n) { float* p = ws + off; off += n; return p; };
    float* h1[3]; h1[0] = alloc(524288); h1[1] = alloc(524288); h1[2] = alloc(524288);
    float* c1 = alloc(524288);
    unsigned short* p1hi = (unsigned short*)alloc(1048576); // 2097152 u16
    unsigned short* p1lo = (unsigned short*)alloc(1048576);
    float* h2[2]; h2[0] = alloc(196608); h2[1] = alloc(196608);
    float* c2 = alloc(196608);
    unsigned short* p2hi = (unsigned short*)alloc(196608);  // 393216 u16
    unsigned short* p2lo = (unsigned short*)alloc(196608);
    float* part = alloc(344064);          // (12,256,112)
    unsigned short* w1F = (unsigned short*)alloc(49152);    // 2 planes
    unsigned short* w2F = (unsigned short*)alloc(147456);
    unsigned short* w3F = (unsigned short*)alloc(2359296);
    float* w4T = alloc(32768);
    float* w5T = alloc(11264);
    (void)ws_size; (void)off;  // ~32.5 MB total

    hipMemsetAsync(h1[2], 0, 524288 * sizeof(float), stream);
    hipMemsetAsync(c1,    0, 524288 * sizeof(float), stream);
    hipMemsetAsync(h2[1], 0, 196608 * sizeof(float), stream);
    hipMemsetAsync(c2,    0, 196608 * sizeof(float), stream);

    prep<<<10156, 256, 0, stream>>>(w1, w2, w3, w4, w5, w1F, w2F, w3F, w4T, w5T);

    for (int t = 0; t < 32; ++t) {
        lstm1_step<<<dim3(4, 8, 8), 512, 0, stream>>>(
            x, w1F, b1, h1[(t + 2) % 3], h1[(t + 1) % 3], h1[t % 3], c1,
            p1hi, p1lo, t);
    }
    pool1k<<<512, 256, 0, stream>>>(h1[0], h1[1], p1hi, p1lo, 15); // t=30,31

    for (int t = 0; t < 16; ++t) {
        lstm2_step<<<dim3(8, 4, 8), 256, 0, stream>>>(
            p1hi, p1lo, w2F, b2, h2[1 - (t & 1)], c2, h2[t & 1], t);
        if (t & 1)
            pool2<<<192, 256, 0, stream>>>(h2[0], h2[1], p2hi, p2lo, t >> 1);
    }

    conv3_part<<<dim3(16, 12), 256, 0, stream>>>(p2hi, p2lo, w3F, part);
    head<<<112, 256, 0, stream>>>(part, b3, w4T, b4, w5T, b5, out);
}